// Round 3
// baseline (634.073 us; speedup 1.0000x reference)
//
#include <hip/hip_runtime.h>
#include <math.h>

#define B_ 16
#define C_ 64
#define H_ 64
#define W_ 64

// ---------------------------------------------------------------------------
// Kernel A: q = relu(bn(conv1x1(x,wq))), k = relu(bn(conv3x3(x,wk))),
//           v = bn(conv1x1(x,wv)).  One block per (batch, row).
// 256 threads: thread = (column px = tid&63, out-channel group g = tid>>6,
// 16 out-channels per thread).
// ---------------------------------------------------------------------------
__global__ __launch_bounds__(256) void qkv_kernel(
    const float* __restrict__ x,
    const float* __restrict__ wq, const float* __restrict__ wk, const float* __restrict__ wv,
    const float* __restrict__ qg, const float* __restrict__ qb, const float* __restrict__ qm, const float* __restrict__ qvar,
    const float* __restrict__ kg, const float* __restrict__ kb, const float* __restrict__ km, const float* __restrict__ kvar,
    const float* __restrict__ vg, const float* __restrict__ vb, const float* __restrict__ vm, const float* __restrict__ vvar,
    float* __restrict__ qo, float* __restrict__ ko, float* __restrict__ vo)
{
    __shared__ float xs[C_][3][66];   // 64 ch x 3 rows x (64+2 halo) cols, 50.7 KB

    const int bid = blockIdx.x;
    const int b   = bid >> 6;
    const int row = bid & 63;
    const int tid = threadIdx.x;

    // cooperative load of x tile (rows row-1..row+1, cols -1..64, all 64 ch)
    for (int idx = tid; idx < C_ * 3 * 66; idx += 256) {
        int ci  = idx / 198;
        int r   = idx - ci * 198;
        int dy  = r / 66;
        int col = r - dy * 66;
        int gh  = row - 1 + dy;
        int gw  = col - 1;
        float val = 0.f;
        if ((unsigned)gh < 64u && (unsigned)gw < 64u)
            val = x[((b * C_ + ci) * H_ + gh) * W_ + gw];
        (&xs[0][0][0])[idx] = val;
    }
    __syncthreads();

    const int px = tid & 63;
    const int g  = tid >> 6;

    float aq[16], ak[16], av[16];
#pragma unroll
    for (int j = 0; j < 16; j++) { aq[j] = 0.f; ak[j] = 0.f; av[j] = 0.f; }

    for (int ci = 0; ci < C_; ci++) {
        float t00 = xs[ci][0][px + 0], t01 = xs[ci][0][px + 1], t02 = xs[ci][0][px + 2];
        float t10 = xs[ci][1][px + 0], t11 = xs[ci][1][px + 1], t12 = xs[ci][1][px + 2];
        float t20 = xs[ci][2][px + 0], t21 = xs[ci][2][px + 1], t22 = xs[ci][2][px + 2];
#pragma unroll
        for (int j = 0; j < 16; j++) {
            int co = g * 16 + j;
            aq[j] = fmaf(wq[co * C_ + ci], t11, aq[j]);
            av[j] = fmaf(wv[co * C_ + ci], t11, av[j]);
            const float* wp = wk + (size_t)(co * C_ + ci) * 9;
            float s = ak[j];
            s = fmaf(wp[0], t00, s); s = fmaf(wp[1], t01, s); s = fmaf(wp[2], t02, s);
            s = fmaf(wp[3], t10, s); s = fmaf(wp[4], t11, s); s = fmaf(wp[5], t12, s);
            s = fmaf(wp[6], t20, s); s = fmaf(wp[7], t21, s); s = fmaf(wp[8], t22, s);
            ak[j] = s;
        }
    }

#pragma unroll
    for (int j = 0; j < 16; j++) {
        int co = g * 16 + j;
        float iq = qg[co] * rsqrtf(qvar[co] + 1e-5f);
        float q_ = fmaxf(fmaf(aq[j], iq, qb[co] - qm[co] * iq), 0.f);
        float ik = kg[co] * rsqrtf(kvar[co] + 1e-5f);
        float k_ = fmaxf(fmaf(ak[j], ik, kb[co] - km[co] * ik), 0.f);
        float iv = vg[co] * rsqrtf(vvar[co] + 1e-5f);
        float v_ = fmaf(av[j], iv, vb[co] - vm[co] * iv);
        int o = ((b * C_ + co) * H_ + row) * W_ + px;
        qo[o] = q_;
        ko[o] = k_;
        vo[o] = v_;
    }
}

// ---------------------------------------------------------------------------
// Kernel B: local attention.  One thread per pixel, all 8 heads.
// NOTE: out-of-bounds taps still get the positional bias in the logit
// (unfold gives 0, then +pos), but contribute 0 to the v-aggregation.
// ---------------------------------------------------------------------------
__global__ __launch_bounds__(256) void attn_kernel(
    const float* __restrict__ q, const float* __restrict__ k, const float* __restrict__ v,
    const float* __restrict__ ph, const float* __restrict__ pw,
    const float* __restrict__ og, const float* __restrict__ ob,
    const float* __restrict__ om, const float* __restrict__ ovar,
    float* __restrict__ out)
{
    const int flat = blockIdx.x * 256 + threadIdx.x;
    const int b = flat >> 12;
    const int h = (flat >> 6) & 63;
    const int w = flat & 63;

    for (int head = 0; head < 8; head++) {
        float qv[8];
#pragma unroll
        for (int c8 = 0; c8 < 8; c8++)
            qv[c8] = q[((b * C_ + head * 8 + c8) * H_ + h) * W_ + w];

        float logit[9];
#pragma unroll
        for (int ky = 0; ky < 3; ky++) {
            int gh = h + ky - 1;
#pragma unroll
            for (int kx = 0; kx < 3; kx++) {
                int gw = w + kx - 1;
                bool inb = ((unsigned)gh < 64u) && ((unsigned)gw < 64u);
                float s = 0.f;
#pragma unroll
                for (int c8 = 0; c8 < 8; c8++) {
                    int c = head * 8 + c8;
                    float pos = ph[c * 3 + ky] + pw[c * 3 + kx];
                    float kk = inb ? k[((b * C_ + c) * H_ + gh) * W_ + gw] : 0.f;
                    s = fmaf(qv[c8], kk + pos, s);
                }
                logit[ky * 3 + kx] = s;
            }
        }

        float m = logit[0];
#pragma unroll
        for (int t = 1; t < 9; t++) m = fmaxf(m, logit[t]);
        float e[9], sum = 0.f;
#pragma unroll
        for (int t = 0; t < 9; t++) { e[t] = __expf(logit[t] - m); sum += e[t]; }
        float inv = 1.f / sum;

#pragma unroll
        for (int c8 = 0; c8 < 8; c8++) {
            int c = head * 8 + c8;
            float acc = 0.f;
#pragma unroll
            for (int ky = 0; ky < 3; ky++) {
                int gh = h + ky - 1;
#pragma unroll
                for (int kx = 0; kx < 3; kx++) {
                    int gw = w + kx - 1;
                    if ((unsigned)gh < 64u && (unsigned)gw < 64u)
                        acc = fmaf(e[ky * 3 + kx], v[((b * C_ + c) * H_ + gh) * W_ + gw], acc);
                }
            }
            acc *= inv;
            float io = og[c] * rsqrtf(ovar[c] + 1e-5f);
            float o_ = fmaxf(fmaf(acc, io, ob[c] - om[c] * io), 0.f);
            out[((b * C_ + c) * H_ + h) * W_ + w] = o_;
        }
    }
}

// ---------------------------------------------------------------------------
extern "C" void kernel_launch(void* const* d_in, const int* in_sizes, int n_in,
                              void* d_out, int out_size, void* d_ws, size_t ws_size,
                              hipStream_t stream)
{
    const float* x   = (const float*)d_in[0];
    const float* wq  = (const float*)d_in[1];
    const float* wk  = (const float*)d_in[2];
    const float* wv  = (const float*)d_in[3];
    const float* ph  = (const float*)d_in[4];
    const float* pw  = (const float*)d_in[5];
    const float* qg  = (const float*)d_in[6];
    const float* qb  = (const float*)d_in[7];
    const float* qm  = (const float*)d_in[8];
    const float* qvar= (const float*)d_in[9];
    const float* kg  = (const float*)d_in[10];
    const float* kb  = (const float*)d_in[11];
    const float* km  = (const float*)d_in[12];
    const float* kvar= (const float*)d_in[13];
    const float* vg  = (const float*)d_in[14];
    const float* vb  = (const float*)d_in[15];
    const float* vm  = (const float*)d_in[16];
    const float* vvar= (const float*)d_in[17];
    const float* og  = (const float*)d_in[18];
    const float* ob  = (const float*)d_in[19];
    const float* om  = (const float*)d_in[20];
    const float* ovar= (const float*)d_in[21];

    const size_t plane = (size_t)B_ * C_ * H_ * W_;   // 4.19M floats
    float* qo = (float*)d_ws;
    float* ko = qo + plane;
    float* vo = ko + plane;

    qkv_kernel<<<B_ * H_, 256, 0, stream>>>(
        x, wq, wk, wv,
        qg, qb, qm, qvar, kg, kb, km, kvar, vg, vb, vm, vvar,
        qo, ko, vo);

    attn_kernel<<<B_ * H_ * W_ / 256, 256, 0, stream>>>(
        qo, ko, vo, ph, pw, og, ob, om, ovar, (float*)d_out);
}

// Round 6
// 188.569 us; speedup vs baseline: 3.3626x; 3.3626x over previous
//
#include <hip/hip_runtime.h>
#include <hip/hip_bf16.h>
#include <math.h>

#define B_ 16
#define C_ 64
#define H_ 64
#define W_ 64
// GEMM: M=192 (q|k|v out-channels), K=576 (tap*64+c), N=64 pixels per block
#define KSTEPS 18

typedef __attribute__((ext_vector_type(8))) short bf16x8;
typedef __attribute__((ext_vector_type(4))) float f32x4;

static __device__ __forceinline__ unsigned short f2b(float f) {
    __hip_bfloat16 h = __float2bfloat16(f);
    return *reinterpret_cast<unsigned short*>(&h);
}
static __device__ __forceinline__ float b2f(unsigned short u) {
    __hip_bfloat16 h;
    *reinterpret_cast<unsigned short*>(&h) = u;
    return __bfloat162float(h);
}

// ---------------------------------------------------------------------------
// prep: pack Wp (bf16, A-frag order: [(mf*18+ks)*64+lane]*8) and bnp
// (f32 [plane][{inv,bias}][64], plane 0=q 1=k 2=v 3=o).
// mf 0-3 -> wq (center tap only), 4-7 -> wk, 8-11 -> wv (center tap only).
// k index = tap*64 + c, tap = ky*3+kx.
// ---------------------------------------------------------------------------
__global__ __launch_bounds__(64) void prep_kernel(
    const float* __restrict__ wq, const float* __restrict__ wk, const float* __restrict__ wv,
    const float* __restrict__ qg, const float* __restrict__ qb, const float* __restrict__ qm, const float* __restrict__ qv,
    const float* __restrict__ kg, const float* __restrict__ kb, const float* __restrict__ km, const float* __restrict__ kv,
    const float* __restrict__ vg, const float* __restrict__ vb, const float* __restrict__ vm, const float* __restrict__ vv,
    const float* __restrict__ og, const float* __restrict__ ob, const float* __restrict__ om, const float* __restrict__ ov,
    unsigned short* __restrict__ Wp, float* __restrict__ bnp)
{
    const int bid = blockIdx.x;
    const int lane = threadIdx.x;
    if (bid < 12 * KSTEPS) {
        const int mf = bid / KSTEPS;
        const int ks = bid % KSTEPS;
        const int r = lane & 15;          // A row within fragment
        bf16x8 u;
#pragma unroll
        for (int j = 0; j < 8; j++) {
            int k = ks * 32 + ((lane >> 4) << 3) + j;
            int tap = k >> 6;
            int c = k & 63;
            float w;
            if (mf < 4)      { int co = mf * 16 + r;        w = (tap == 4) ? wq[co * 64 + c] : 0.f; }
            else if (mf < 8) { int co = (mf - 4) * 16 + r;  w = wk[(co * 64 + c) * 9 + tap]; }
            else             { int co = (mf - 8) * 16 + r;  w = (tap == 4) ? wv[co * 64 + c] : 0.f; }
            u[j] = (short)f2b(w);
        }
        *reinterpret_cast<bf16x8*>(Wp + ((size_t)(mf * KSTEPS + ks) * 64 + lane) * 8) = u;
    } else {
        const int c = lane;
        const float* G[4] = {qg, kg, vg, og};
        const float* Bt[4] = {qb, kb, vb, ob};
        const float* M[4] = {qm, km, vm, om};
        const float* V[4] = {qv, kv, vv, ov};
#pragma unroll
        for (int p = 0; p < 4; p++) {
            float inv = G[p][c] * rsqrtf(V[p][c] + 1e-5f);
            bnp[p * 128 + c] = inv;
            bnp[p * 128 + 64 + c] = Bt[p][c] - M[p][c] * inv;
        }
    }
}

// ---------------------------------------------------------------------------
// qkv via MFMA implicit GEMM.  One block per (b, output row). 4 waves.
// LDS: xs = bf16 x-tile [3 rows][66 cols][64 ch], XOR-swizzled (byte ^= (col&7)<<4)
//      reused after barrier as xp = f32 [64 px][196] transpose buffer.
// Outputs: q/k/v planes bf16, channel-fastest: plane[((b*64+h)*64+px)*64 + c].
// ---------------------------------------------------------------------------
__global__ __launch_bounds__(256) void qkv_mfma(
    const float* __restrict__ x, const unsigned short* __restrict__ Wp,
    const float* __restrict__ bnp,
    unsigned short* __restrict__ qt, unsigned short* __restrict__ kt, unsigned short* __restrict__ vt)
{
    __shared__ __align__(16) char smem[64 * 196 * 4];   // 50176 B
    const int bid = blockIdx.x;
    const int b = bid >> 6;
    const int h = bid & 63;
    const int tid = threadIdx.x;

    // ---- stage x tile (f32 -> bf16, swizzled) ----
    for (int i = tid; i < 3 * 66 * 8; i += 256) {
        int col = i % 66;                  // lane-adjacent -> coalesced along width
        int dy  = (i / 66) % 3;
        int c0g = i / 198;                 // channel group of 8
        int gh = h + dy - 1, gw = col - 1;
        bool ok = ((unsigned)gh < 64u) && ((unsigned)gw < 64u);
        bf16x8 u;
#pragma unroll
        for (int j = 0; j < 8; j++) {
            float f = ok ? x[((b * 64 + c0g * 8 + j) * 64 + gh) * 64 + gw] : 0.f;
            u[j] = (short)f2b(f);
        }
        int La = ((dy * 66 + col) * 64 + c0g * 8) * 2;
        La ^= (col & 7) << 4;
        *reinterpret_cast<bf16x8*>(smem + La) = u;
    }
    __syncthreads();

    // ---- MFMA main loop ----
    const int wid = tid >> 6, lane = tid & 63;
    f32x4 acc[3][4];
#pragma unroll
    for (int m = 0; m < 3; m++)
#pragma unroll
        for (int nf = 0; nf < 4; nf++) acc[m][nf] = (f32x4){0.f, 0.f, 0.f, 0.f};

    for (int ks = 0; ks < KSTEPS; ks++) {
        const int tap = ks >> 1;
        const int dy = tap / 3, dx = tap - dy * 3;
        const int c0 = (ks & 1) * 32 + ((lane >> 4) << 3);
        bf16x8 bf[4];
#pragma unroll
        for (int nf = 0; nf < 4; nf++) {
            int col = nf * 16 + (lane & 15) + dx;
            int La = ((dy * 66 + col) * 64 + c0) * 2;
            La ^= (col & 7) << 4;
            bf[nf] = *reinterpret_cast<const bf16x8*>(smem + La);
        }
#pragma unroll
        for (int m = 0; m < 3; m++) {
            int mf = wid * 3 + m;
            bf16x8 af = *reinterpret_cast<const bf16x8*>(Wp + ((size_t)(mf * KSTEPS + ks) * 64 + lane) * 8);
#pragma unroll
            for (int nf = 0; nf < 4; nf++)
                acc[m][nf] = __builtin_amdgcn_mfma_f32_16x16x32_bf16(af, bf[nf], acc[m][nf], 0, 0, 0);
        }
    }
    __syncthreads();

    // ---- epilogue: BN(+ReLU for q,k), transpose through LDS ----
    float* xp = reinterpret_cast<float*>(smem);   // [64][196]
#pragma unroll
    for (int m = 0; m < 3; m++) {
        int mf = wid * 3 + m;
        int plane = mf >> 2;
#pragma unroll
        for (int nf = 0; nf < 4; nf++) {
            int px = nf * 16 + (lane & 15);
            int cobase = mf * 16 + ((lane >> 4) << 2);   // global co (0..191)
#pragma unroll
            for (int r = 0; r < 3 + 1; r++) {
                int c = (cobase + r) & 63;
                float inv = bnp[plane * 128 + c];
                float bias = bnp[plane * 128 + 64 + c];
                float val = acc[m][nf][r] * inv + bias;
                if (plane < 2) val = fmaxf(val, 0.f);
                xp[px * 196 + cobase + r] = val;
            }
        }
    }
    __syncthreads();

    if (tid < 192) {
        int px = tid & 63, plane = tid >> 6;
        unsigned short* dst = (plane == 0 ? qt : plane == 1 ? kt : vt)
                              + ((size_t)((b * 64 + h) * 64 + px)) * 64;
        for (int j = 0; j < 64; j += 8) {
            bf16x8 u;
#pragma unroll
            for (int t = 0; t < 8; t++)
                u[t] = (short)f2b(xp[px * 196 + plane * 64 + j + t]);
            *reinterpret_cast<bf16x8*>(dst + j) = u;
        }
    }
}

// ---------------------------------------------------------------------------
// attn v2: thread = (pixel, head).  2048 blocks x 256 threads.
// logit[tap] = sum_c q*(k) + A[ky] + B[kx]  (pos decomposed; OOB taps keep
// pos-only logit, contribute 0 to PV — matches unfold-then-add-pos semantics).
// ---------------------------------------------------------------------------
__global__ __launch_bounds__(256) void attn2_kernel(
    const unsigned short* __restrict__ qt, const unsigned short* __restrict__ kt,
    const unsigned short* __restrict__ vt,
    const float* __restrict__ ph, const float* __restrict__ pw,
    const float* __restrict__ bnp, float* __restrict__ out)
{
    const int bid = blockIdx.x;
    const int hh = bid & 1;               // head half
    const int h = (bid >> 1) & 63;
    const int b = bid >> 7;
    const int px = threadIdx.x & 63;
    const int head = hh * 4 + (threadIdx.x >> 6);
    const int cb = head * 8;              // channel base

    // q (8 ch, bf16)
    float qf[8];
    {
        bf16x8 q8 = *reinterpret_cast<const bf16x8*>(qt + ((size_t)((b * 64 + h) * 64 + px)) * 64 + cb);
#pragma unroll
        for (int j = 0; j < 8; j++) qf[j] = b2f((unsigned short)q8[j]);
    }

    // positional dot products (wave-uniform ph/pw reads)
    float A[3], Bx[3];
#pragma unroll
    for (int t = 0; t < 3; t++) {
        float a = 0.f, bb = 0.f;
#pragma unroll
        for (int j = 0; j < 8; j++) {
            a  = fmaf(qf[j], ph[(cb + j) * 3 + t], a);
            bb = fmaf(qf[j], pw[(cb + j) * 3 + t], bb);
        }
        A[t] = a; Bx[t] = bb;
    }

    float logit[9];
#pragma unroll
    for (int ky = 0; ky < 3; ky++) {
        int gh = h + ky - 1;
        bool rok = (unsigned)gh < 64u;
#pragma unroll
        for (int kx = 0; kx < 3; kx++) {
            int gw = px + kx - 1;
            bool ok = rok && ((unsigned)gw < 64u);
            float qk = 0.f;
            if (ok) {
                bf16x8 k8 = *reinterpret_cast<const bf16x8*>(kt + ((size_t)((b * 64 + gh) * 64 + gw)) * 64 + cb);
#pragma unroll
                for (int j = 0; j < 8; j++) qk = fmaf(qf[j], b2f((unsigned short)k8[j]), qk);
            }
            logit[ky * 3 + kx] = qk + A[ky] + Bx[kx];
        }
    }

    float m = logit[0];
#pragma unroll
    for (int t = 1; t < 9; t++) m = fmaxf(m, logit[t]);
    float e[9], sum = 0.f;
#pragma unroll
    for (int t = 0; t < 9; t++) { e[t] = __expf(logit[t] - m); sum += e[t]; }
    float inv = 1.f / sum;

    float o[8];
#pragma unroll
    for (int j = 0; j < 8; j++) o[j] = 0.f;
#pragma unroll
    for (int ky = 0; ky < 3; ky++) {
        int gh = h + ky - 1;
        bool rok = (unsigned)gh < 64u;
#pragma unroll
        for (int kx = 0; kx < 3; kx++) {
            int gw = px + kx - 1;
            if (rok && ((unsigned)gw < 64u)) {
                bf16x8 v8 = *reinterpret_cast<const bf16x8*>(vt + ((size_t)((b * 64 + gh) * 64 + gw)) * 64 + cb);
                float w = e[ky * 3 + kx];
#pragma unroll
                for (int j = 0; j < 8; j++) o[j] = fmaf(w, b2f((unsigned short)v8[j]), o[j]);
            }
        }
    }

#pragma unroll
    for (int j = 0; j < 8; j++) {
        int c = cb + j;
        float io = bnp[3 * 128 + c];
        float bo = bnp[3 * 128 + 64 + c];
        float val = fmaxf(fmaf(o[j] * inv, io, bo), 0.f);
        out[((size_t)(b * C_ + c) * H_ + h) * W_ + px] = val;
    }
}

// ---------------------------------------------------------------------------
extern "C" void kernel_launch(void* const* d_in, const int* in_sizes, int n_in,
                              void* d_out, int out_size, void* d_ws, size_t ws_size,
                              hipStream_t stream)
{
    const float* x   = (const float*)d_in[0];
    const float* wq  = (const float*)d_in[1];
    const float* wk  = (const float*)d_in[2];
    const float* wv  = (const float*)d_in[3];
    const float* ph  = (const float*)d_in[4];
    const float* pw  = (const float*)d_in[5];
    const float* qg  = (const float*)d_in[6];
    const float* qb  = (const float*)d_in[7];
    const float* qm  = (const float*)d_in[8];
    const float* qv  = (const float*)d_in[9];
    const float* kg  = (const float*)d_in[10];
    const float* kb  = (const float*)d_in[11];
    const float* km  = (const float*)d_in[12];
    const float* kv  = (const float*)d_in[13];
    const float* vg  = (const float*)d_in[14];
    const float* vb  = (const float*)d_in[15];
    const float* vm  = (const float*)d_in[16];
    const float* vv  = (const float*)d_in[17];
    const float* og  = (const float*)d_in[18];
    const float* ob  = (const float*)d_in[19];
    const float* om  = (const float*)d_in[20];
    const float* ov  = (const float*)d_in[21];

    char* ws = (char*)d_ws;
    unsigned short* Wp = (unsigned short*)ws;                 // 221184 B
    float* bnp = (float*)(ws + 221184);                       // 2048 B
    unsigned short* qt = (unsigned short*)(ws + 223232);      // 8.39 MB each
    unsigned short* kt = qt + (size_t)B_ * H_ * W_ * C_;
    unsigned short* vt = kt + (size_t)B_ * H_ * W_ * C_;

    prep_kernel<<<12 * KSTEPS + 1, 64, 0, stream>>>(
        wq, wk, wv, qg, qb, qm, qv, kg, kb, km, kv, vg, vb, vm, vv,
        og, ob, om, ov, Wp, bnp);

    qkv_mfma<<<B_ * H_, 256, 0, stream>>>(x, Wp, bnp, qt, kt, vt);

    attn2_kernel<<<B_ * H_ * 2, 256, 0, stream>>>(qt, kt, vt, ph, pw, bnp, (float*)d_out);
}

// Round 7
// 156.340 us; speedup vs baseline: 4.0557x; 1.2061x over previous
//
#include <hip/hip_runtime.h>
#include <hip/hip_bf16.h>
#include <math.h>

#define B_ 16
#define C_ 64
#define H_ 64
#define W_ 64
#define KSTEPS 18

typedef __attribute__((ext_vector_type(8))) short bf16x8;
typedef __attribute__((ext_vector_type(4))) short bf16x4;
typedef __attribute__((ext_vector_type(4))) float f32x4;

static __device__ __forceinline__ unsigned short f2b(float f) {
    __hip_bfloat16 h = __float2bfloat16(f);
    return *reinterpret_cast<unsigned short*>(&h);
}
static __device__ __forceinline__ float b2f(unsigned short u) {
    __hip_bfloat16 h;
    *reinterpret_cast<unsigned short*>(&h) = u;
    return __bfloat162float(h);
}

// ---------------------------------------------------------------------------
// prep: pack Wp (bf16, A-frag order) + bnp (f32 [plane][{inv,bias}][64]).
// k index = tap*64 + c, tap = ky*3+kx.  (unchanged from round 6 — verified)
// ---------------------------------------------------------------------------
__global__ __launch_bounds__(64) void prep_kernel(
    const float* __restrict__ wq, const float* __restrict__ wk, const float* __restrict__ wv,
    const float* __restrict__ qg, const float* __restrict__ qb, const float* __restrict__ qm, const float* __restrict__ qv,
    const float* __restrict__ kg, const float* __restrict__ kb, const float* __restrict__ km, const float* __restrict__ kv,
    const float* __restrict__ vg, const float* __restrict__ vb, const float* __restrict__ vm, const float* __restrict__ vv,
    const float* __restrict__ og, const float* __restrict__ ob, const float* __restrict__ om, const float* __restrict__ ov,
    unsigned short* __restrict__ Wp, float* __restrict__ bnp)
{
    const int bid = blockIdx.x;
    const int lane = threadIdx.x;
    if (bid < 12 * KSTEPS) {
        const int mf = bid / KSTEPS;
        const int ks = bid % KSTEPS;
        const int r = lane & 15;
        bf16x8 u;
#pragma unroll
        for (int j = 0; j < 8; j++) {
            int k = ks * 32 + ((lane >> 4) << 3) + j;
            int tap = k >> 6;
            int c = k & 63;
            float w;
            if (mf < 4)      { int co = mf * 16 + r;        w = (tap == 4) ? wq[co * 64 + c] : 0.f; }
            else if (mf < 8) { int co = (mf - 4) * 16 + r;  w = wk[(co * 64 + c) * 9 + tap]; }
            else             { int co = (mf - 8) * 16 + r;  w = (tap == 4) ? wv[co * 64 + c] : 0.f; }
            u[j] = (short)f2b(w);
        }
        *reinterpret_cast<bf16x8*>(Wp + ((size_t)(mf * KSTEPS + ks) * 64 + lane) * 8) = u;
    } else {
        const int c = lane;
        const float* G[4] = {qg, kg, vg, og};
        const float* Bt[4] = {qb, kb, vb, ob};
        const float* M[4] = {qm, km, vm, om};
        const float* V[4] = {qv, kv, vv, ov};
#pragma unroll
        for (int p = 0; p < 4; p++) {
            float inv = G[p][c] * rsqrtf(V[p][c] + 1e-5f);
            bnp[p * 128 + c] = inv;
            bnp[p * 128 + 64 + c] = Bt[p][c] - M[p][c] * inv;
        }
    }
}

// ---------------------------------------------------------------------------
// qkv v2: 2 output rows per block, 512 threads (8 waves = 4 mf-groups x 2
// nf-groups).  M=192, K=576, N=128 px.  LDS x-tile [4 rows][66 cols][64 c]
// bf16, XOR-swizzled (byte ^= (col&7)<<4).  Epilogue: BN in-register,
// direct bf16x4 global stores from the C-frag (no LDS transpose).
// ---------------------------------------------------------------------------
__global__ __launch_bounds__(512) void qkv_mfma2(
    const float* __restrict__ x, const unsigned short* __restrict__ Wp,
    const float* __restrict__ bnp,
    unsigned short* __restrict__ qt, unsigned short* __restrict__ kt, unsigned short* __restrict__ vt)
{
    __shared__ __align__(16) char xs[4 * 66 * 64 * 2];   // 33792 B
    __shared__ float bns[384];
    const int bid = blockIdx.x;
    const int b  = bid >> 5;
    const int h0 = (bid & 31) << 1;
    const int tid = threadIdx.x;

    // ---- stage x rows h0-1 .. h0+2 ----
    for (int i = tid; i < 4 * 66 * 8; i += 512) {
        int col = i % 66;
        int dy  = (i / 66) & 3;
        int c0g = i / 264;
        int gh = h0 - 1 + dy, gw = col - 1;
        bool ok = ((unsigned)gh < 64u) && ((unsigned)gw < 64u);
        bf16x8 u;
#pragma unroll
        for (int j = 0; j < 8; j++) {
            float f = ok ? x[((b * 64 + c0g * 8 + j) * 64 + gh) * 64 + gw] : 0.f;
            u[j] = (short)f2b(f);
        }
        int La = ((dy * 66 + col) * 64 + c0g * 8) * 2;
        La ^= (col & 7) << 4;
        *reinterpret_cast<bf16x8*>(xs + La) = u;
    }
    if (tid < 384) bns[tid] = bnp[tid];
    __syncthreads();

    const int wid = tid >> 6, lane = tid & 63;
    const int mfg = wid >> 1, nfg = wid & 1;
    const int t = lane & 15, q4 = lane >> 4;

    f32x4 acc[3][4];
#pragma unroll
    for (int m = 0; m < 3; m++)
#pragma unroll
        for (int n = 0; n < 4; n++) acc[m][n] = (f32x4){0.f, 0.f, 0.f, 0.f};

    for (int ks = 0; ks < KSTEPS; ks++) {
        const int tap = ks >> 1;
        const int dy = tap / 3, dx = tap - dy * 3;
        const int kb = (ks & 1) * 32 + q4 * 8;   // c-base within tap
        bf16x8 bf[4];
#pragma unroll
        for (int n = 0; n < 4; n++) {
            int p = (nfg * 4 + n) * 16 + t;      // global px 0..127
            int r = p >> 6, colw = p & 63;
            int col = colw + dx;
            int La = (((r + dy) * 66 + col) * 64 + kb) * 2;
            La ^= (col & 7) << 4;
            bf[n] = *reinterpret_cast<const bf16x8*>(xs + La);
        }
#pragma unroll
        for (int m = 0; m < 3; m++) {
            int mf = mfg * 3 + m;
            bf16x8 af = *reinterpret_cast<const bf16x8*>(Wp + ((size_t)(mf * KSTEPS + ks) * 64 + lane) * 8);
#pragma unroll
            for (int n = 0; n < 4; n++)
                acc[m][n] = __builtin_amdgcn_mfma_f32_16x16x32_bf16(af, bf[n], acc[m][n], 0, 0, 0);
        }
    }

    // ---- epilogue: BN(+ReLU q,k) in-register, direct bf16x4 stores ----
#pragma unroll
    for (int m = 0; m < 3; m++) {
        int mf = mfg * 3 + m;
        int plane = mf >> 2;
        int co0 = mf * 16 + q4 * 4;     // global co quad base (0..188)
        int c0 = co0 & 63;
        f32x4 inv  = *reinterpret_cast<const f32x4*>(&bns[plane * 128 + c0]);
        f32x4 bias = *reinterpret_cast<const f32x4*>(&bns[plane * 128 + 64 + c0]);
        unsigned short* base = (plane == 0 ? qt : plane == 1 ? kt : vt);
#pragma unroll
        for (int n = 0; n < 4; n++) {
            int p = (nfg * 4 + n) * 16 + t;
            int r = p >> 6, colw = p & 63;
            bf16x4 pack;
#pragma unroll
            for (int j = 0; j < 4; j++) {
                float val = acc[m][n][j] * inv[j] + bias[j];
                if (plane < 2) val = fmaxf(val, 0.f);
                pack[j] = (short)f2b(val);
            }
            *reinterpret_cast<bf16x4*>(base + ((size_t)((b * 64 + h0 + r) * 64 + colw)) * 64 + c0) = pack;
        }
    }
}

// ---------------------------------------------------------------------------
// attn v3: block = (b, row), 512 threads = 64 px x 8 heads (wave = one head).
// k,v rows h-1..h+1 staged in LDS [3][66 px'][64 c] bf16, XOR-swizzled
// (byte ^= (px'&7)<<4); px' = gw+1, zero-filled OOB => logit = pos-only and
// PV contribution 0 for OOB taps automatically (reference semantics).
// ---------------------------------------------------------------------------
__global__ __launch_bounds__(512) void attn3_kernel(
    const unsigned short* __restrict__ qt, const unsigned short* __restrict__ kt,
    const unsigned short* __restrict__ vt,
    const float* __restrict__ ph, const float* __restrict__ pw,
    const float* __restrict__ bnp, float* __restrict__ out)
{
    __shared__ __align__(16) char ksm[3 * 66 * 64 * 2];   // 25344 B
    __shared__ __align__(16) char vsm[3 * 66 * 64 * 2];
    __shared__ float bno[128];
    const int bid = blockIdx.x;
    const int b = bid >> 6;
    const int h = bid & 63;
    const int tid = threadIdx.x;

    // ---- stage k,v ----
    for (int i = tid; i < 3 * 66 * 8; i += 512) {
        int c8  = i & 7;
        int pxp = (i >> 3) % 66;
        int dy  = (i >> 3) / 66;
        int gh = h + dy - 1, gw = pxp - 1;
        bool ok = ((unsigned)gh < 64u) && ((unsigned)gw < 64u);
        int La = ((dy * 66 + pxp) * 64 + c8 * 8) * 2;
        La ^= (pxp & 7) << 4;
        bf16x8 kk = (bf16x8){0,0,0,0,0,0,0,0}, vv = kk;
        if (ok) {
            size_t src = ((size_t)((b * 64 + gh) * 64 + gw)) * 64 + c8 * 8;
            kk = *reinterpret_cast<const bf16x8*>(kt + src);
            vv = *reinterpret_cast<const bf16x8*>(vt + src);
        }
        *reinterpret_cast<bf16x8*>(ksm + La) = kk;
        *reinterpret_cast<bf16x8*>(vsm + La) = vv;
    }
    if (tid < 128) bno[tid] = bnp[384 + tid];
    __syncthreads();

    const int px = tid & 63;
    const int head = tid >> 6;
    const int cb = head * 8;

    float qf[8];
    {
        bf16x8 q8 = *reinterpret_cast<const bf16x8*>(qt + ((size_t)((b * 64 + h) * 64 + px)) * 64 + cb);
#pragma unroll
        for (int j = 0; j < 8; j++) qf[j] = b2f((unsigned short)q8[j]);
    }

    float A[3], Bx[3];
#pragma unroll
    for (int tt = 0; tt < 3; tt++) {
        float a = 0.f, bb = 0.f;
#pragma unroll
        for (int j = 0; j < 8; j++) {
            a  = fmaf(qf[j], ph[(cb + j) * 3 + tt], a);
            bb = fmaf(qf[j], pw[(cb + j) * 3 + tt], bb);
        }
        A[tt] = a; Bx[tt] = bb;
    }

    float logit[9];
#pragma unroll
    for (int dy = 0; dy < 3; dy++) {
#pragma unroll
        for (int dx = 0; dx < 3; dx++) {
            int pxp = px + dx;
            int La = ((dy * 66 + pxp) * 64 + cb) * 2;
            La ^= (pxp & 7) << 4;
            bf16x8 k8 = *reinterpret_cast<const bf16x8*>(ksm + La);
            float qk = 0.f;
#pragma unroll
            for (int j = 0; j < 8; j++) qk = fmaf(qf[j], b2f((unsigned short)k8[j]), qk);
            logit[dy * 3 + dx] = qk + A[dy] + Bx[dx];
        }
    }

    float m = logit[0];
#pragma unroll
    for (int tt = 1; tt < 9; tt++) m = fmaxf(m, logit[tt]);
    float e[9], sum = 0.f;
#pragma unroll
    for (int tt = 0; tt < 9; tt++) { e[tt] = __expf(logit[tt] - m); sum += e[tt]; }
    float inv = 1.f / sum;

    float o[8];
#pragma unroll
    for (int j = 0; j < 8; j++) o[j] = 0.f;
#pragma unroll
    for (int dy = 0; dy < 3; dy++) {
#pragma unroll
        for (int dx = 0; dx < 3; dx++) {
            int pxp = px + dx;
            int La = ((dy * 66 + pxp) * 64 + cb) * 2;
            La ^= (pxp & 7) << 4;
            bf16x8 v8 = *reinterpret_cast<const bf16x8*>(vsm + La);
            float w = e[dy * 3 + dx];
#pragma unroll
            for (int j = 0; j < 8; j++) o[j] = fmaf(w, b2f((unsigned short)v8[j]), o[j]);
        }
    }

#pragma unroll
    for (int j = 0; j < 8; j++) {
        int c = cb + j;
        float val = fmaxf(fmaf(o[j] * inv, bno[c], bno[64 + c]), 0.f);
        out[((size_t)(b * C_ + c) * H_ + h) * W_ + px] = val;
    }
}

// ---------------------------------------------------------------------------
extern "C" void kernel_launch(void* const* d_in, const int* in_sizes, int n_in,
                              void* d_out, int out_size, void* d_ws, size_t ws_size,
                              hipStream_t stream)
{
    const float* x   = (const float*)d_in[0];
    const float* wq  = (const float*)d_in[1];
    const float* wk  = (const float*)d_in[2];
    const float* wv  = (const float*)d_in[3];
    const float* ph  = (const float*)d_in[4];
    const float* pw  = (const float*)d_in[5];
    const float* qg  = (const float*)d_in[6];
    const float* qb  = (const float*)d_in[7];
    const float* qm  = (const float*)d_in[8];
    const float* qv  = (const float*)d_in[9];
    const float* kg  = (const float*)d_in[10];
    const float* kb  = (const float*)d_in[11];
    const float* km  = (const float*)d_in[12];
    const float* kv  = (const float*)d_in[13];
    const float* vg  = (const float*)d_in[14];
    const float* vb  = (const float*)d_in[15];
    const float* vm  = (const float*)d_in[16];
    const float* vv  = (const float*)d_in[17];
    const float* og  = (const float*)d_in[18];
    const float* ob  = (const float*)d_in[19];
    const float* om  = (const float*)d_in[20];
    const float* ov  = (const float*)d_in[21];

    char* ws = (char*)d_ws;
    unsigned short* Wp = (unsigned short*)ws;                 // 221184 B
    float* bnp = (float*)(ws + 221184);                       // 2048 B
    unsigned short* qt = (unsigned short*)(ws + 223232);      // 8.39 MB each
    unsigned short* kt = qt + (size_t)B_ * H_ * W_ * C_;
    unsigned short* vt = kt + (size_t)B_ * H_ * W_ * C_;

    prep_kernel<<<12 * KSTEPS + 1, 64, 0, stream>>>(
        wq, wk, wv, qg, qb, qm, qv, kg, kb, km, kv, vg, vb, vm, vv,
        og, ob, om, ov, Wp, bnp);

    qkv_mfma2<<<B_ * H_ / 2, 512, 0, stream>>>(x, Wp, bnp, qt, kt, vt);

    attn3_kernel<<<B_ * H_, 512, 0, stream>>>(qt, kt, vt, ph, pw, bnp, (float*)d_out);
}